// Round 1
// baseline (42741.907 us; speedup 1.0000x reference)
//
#include <hip/hip_runtime.h>
#include <math.h>

#define BDIM 128
#define TDIM 512
#define BT (BDIM*TDIM)

// ---------------------------------------------------------------------------
// Activation helpers (match jax.nn semantics)
// ---------------------------------------------------------------------------
__device__ __forceinline__ float eluf(float v){ return v > 0.f ? v : expm1f(v); }
__device__ __forceinline__ float softplusf(float v){ return fmaxf(v,0.f) + log1pf(expf(-fabsf(v))); }
__device__ __forceinline__ float sigmoidf(float v){ return 1.f/(1.f+expf(-v)); }

// ---------------------------------------------------------------------------
// Generic tiled GEMM:  C[M,N] = epi( X[M,K] @ W_T[K,N] + bias )
// X source is a 2-way concat (x1 for k<split, x2 after; null ptr -> zeros),
// or elu(x1+x2+biask) (reconstructing a hidden layer from K-split partials).
// W is pre-transposed on device to [K][N] row-major (ldw = full N).
// k0/K allow K-splitting across gridDim.z with separate partial outputs.
// ---------------------------------------------------------------------------
struct GemmP {
  const float* x1; long ldx1;
  const float* x2; long ldx2;
  int split;
  const float* w; int ldw;
  const float* biask;     // k-dim bias for ELUSUM source
  const float* bias;      // n-dim output bias
  float* out;  long ldo;
  float* out2;            // PSCALE second output
  int M, N, K, k0;
};

enum { SRC_CONCAT=0, SRC_ELUSUM=1 };
enum { EPI_ELU=0, EPI_PLAIN=1, EPI_PARTIAL=2, EPI_PSCALE=3 };

template<int SRC, int EPI, int BM>
__global__ __launch_bounds__(256) void gemm_k(GemmP pa, GemmP pb)
{
  const GemmP p = (blockIdx.z==0) ? pa : pb;
  constexpr int TM = BM/16;
  __shared__ float  Xs[BM][16];
  __shared__ float4 Ws4[16][16];
  const int tid = threadIdx.x;
  const int nt = tid & 15;
  const int mt = tid >> 4;
  const int n0 = blockIdx.x * 64;
  const int m0 = blockIdx.y * BM;

  float acc[TM][4];
  #pragma unroll
  for (int i=0;i<TM;i++){ acc[i][0]=0.f; acc[i][1]=0.f; acc[i][2]=0.f; acc[i][3]=0.f; }

  const int ktiles = p.K / 16;
  for (int kt=0; kt<ktiles; ++kt){
    const int kbase = p.k0 + kt*16;
    // ---- X tile: BM x 16 (float4 per thread)
    {
      const int nload4 = BM*16/4;
      if (tid < nload4){
        const int mi = tid >> 2;
        const int kk = (tid & 3) * 4;
        const int kabs = kbase + kk;
        float4 v;
        if (SRC == SRC_CONCAT){
          const float* src; long row; int k2;
          if (kabs < p.split){ src = p.x1; row = (long)(m0+mi)*p.ldx1; k2 = kabs; }
          else               { src = p.x2; row = (long)(m0+mi)*p.ldx2; k2 = kabs - p.split; }
          if (src) v = *(const float4*)(src + row + k2);
          else { v.x=0.f; v.y=0.f; v.z=0.f; v.w=0.f; }
        } else { // SRC_ELUSUM: elu(x1 + x2 + biask)
          const long row = (long)(m0+mi)*p.ldx1;
          float4 a = *(const float4*)(p.x1 + row + kabs);
          float4 b = *(const float4*)(p.x2 + row + kabs);
          v.x = eluf(a.x + b.x + p.biask[kabs+0]);
          v.y = eluf(a.y + b.y + p.biask[kabs+1]);
          v.z = eluf(a.z + b.z + p.biask[kabs+2]);
          v.w = eluf(a.w + b.w + p.biask[kabs+3]);
        }
        *(float4*)(&Xs[mi][kk]) = v;
      }
    }
    // ---- W tile: 16 x 64 from transposed [K][N]
    {
      const int kk = tid >> 4;
      const int n4 = (tid & 15) * 4;
      const int n = n0 + n4;
      const long base = (long)(kbase + kk) * p.ldw + n;
      float4 v;
      if (n + 3 < p.N) v = *(const float4*)(p.w + base);
      else {
        v.x = (n+0 < p.N) ? p.w[base+0] : 0.f;
        v.y = (n+1 < p.N) ? p.w[base+1] : 0.f;
        v.z = (n+2 < p.N) ? p.w[base+2] : 0.f;
        v.w = (n+3 < p.N) ? p.w[base+3] : 0.f;
      }
      Ws4[kk][tid & 15] = v;
    }
    __syncthreads();
    #pragma unroll
    for (int kk=0; kk<16; ++kk){
      const float4 w4 = Ws4[kk][nt];
      #pragma unroll
      for (int i=0;i<TM;i++){
        const float xv = Xs[mt*TM+i][kk];
        acc[i][0] = fmaf(xv, w4.x, acc[i][0]);
        acc[i][1] = fmaf(xv, w4.y, acc[i][1]);
        acc[i][2] = fmaf(xv, w4.z, acc[i][2]);
        acc[i][3] = fmaf(xv, w4.w, acc[i][3]);
      }
    }
    __syncthreads();
  }
  // ---- epilogue
  #pragma unroll
  for (int i=0;i<TM;i++){
    const int m = m0 + mt*TM + i;
    #pragma unroll
    for (int j=0;j<4;j++){
      const int n = n0 + nt*4 + j;
      if (n >= p.N) continue;
      float v = acc[i][j];
      if (EPI == EPI_PARTIAL){
        p.out[(long)m*p.ldo + n] = v;
      } else if (EPI == EPI_ELU){
        p.out[(long)m*p.ldo + n] = eluf(v + p.bias[n]);
      } else if (EPI == EPI_PLAIN){
        p.out[(long)m*p.ldo + n] = v + p.bias[n];
      } else { // EPI_PSCALE: n<64 -> shift, n>=64 -> softplus(.)+0.1 -> scale
        v += p.bias[n];
        if (n < 64) p.out [(long)m*64 + n]      = v;
        else        p.out2[(long)m*64 + (n-64)] = softplusf(v) + 0.1f;
      }
    }
  }
}

// ---------------------------------------------------------------------------
// Weight transpose: dst[C][R] <- src[R][C]
// ---------------------------------------------------------------------------
__global__ void transpose_k(const float* __restrict__ src, float* __restrict__ dst, int R, int C){
  __shared__ float tile[32][33];
  const int c0 = blockIdx.x*32, r0 = blockIdx.y*32;
  const int tx = threadIdx.x, ty = threadIdx.y; // 32 x 8
  for (int i=ty; i<32; i+=8){
    const int r = r0+i, c = c0+tx;
    tile[i][tx] = (r<R && c<C) ? src[(long)r*C + c] : 0.f;
  }
  __syncthreads();
  for (int i=ty; i<32; i+=8){
    const int r = r0+tx, c = c0+i;
    if (r<R && c<C) dst[(long)c*R + r] = tile[tx][i];
  }
}

// ---------------------------------------------------------------------------
// GRU gate fusion: det[b,n] from gi/gh [B,1536] and det_prev
// det_prev/det_out are pre-offset by t*512; row stride TDIM*512.
// ---------------------------------------------------------------------------
__global__ void gate_k(const float* __restrict__ gi, const float* __restrict__ gh,
                       const float* __restrict__ det_prev, float* __restrict__ det_out){
  const int idx = blockIdx.x*blockDim.x + threadIdx.x;  // 128*512
  const int b = idx >> 9, n = idx & 511;
  const long g = (long)b*1536 + n;
  const float ir = gi[g], iz = gi[g+512], ia = gi[g+1024];
  const float hr = gh[g], hz = gh[g+512], ha = gh[g+1024];
  const float dp = det_prev ? det_prev[(long)b*TDIM*512 + n] : 0.f;
  const float r = sigmoidf(ir+hr);
  const float z = sigmoidf(iz+hz);
  const float nn = tanhf(ia + r*ha);
  det_out[(long)b*TDIM*512 + n] = (1.f - z)*nn + z*dp;
}

// ---------------------------------------------------------------------------
// Posterior head: q = qa+qb+bias; q_scale = softplus+0.1; stoch = sh + sc*eps
// eps_t / outputs pre-offset by t*64; row stride TDIM*64.
// ---------------------------------------------------------------------------
__global__ void stoch_k(const float* __restrict__ qa, const float* __restrict__ qb,
                        const float* __restrict__ pos_dec_b, const float* __restrict__ eps_t,
                        float* __restrict__ q_sh, float* __restrict__ q_sc, float* __restrict__ st){
  const int idx = blockIdx.x*blockDim.x + threadIdx.x;  // 128*64
  const int b = idx >> 6, s = idx & 63;
  const long q = (long)b*128;
  const float v0 = qa[q+s]    + qb[q+s]    + pos_dec_b[s];
  const float v1 = qa[q+64+s] + qb[q+64+s] + pos_dec_b[64+s];
  const float sc = softplusf(v1) + 0.1f;
  const float e  = eps_t[(long)b*TDIM*64 + s];
  const long o = (long)b*TDIM*64 + s;
  q_sh[o] = v0;
  q_sc[o] = sc;
  st[o]   = v0 + sc*e;
}

// ---------------------------------------------------------------------------
extern "C" void kernel_launch(void* const* d_in, const int* in_sizes, int n_in,
                              void* d_out, int out_size, void* d_ws, size_t ws_size,
                              hipStream_t stream)
{
  const float* obs       = (const float*)d_in[0];
  const float* act       = (const float*)d_in[1];
  const float* eps       = (const float*)d_in[2];
  const float* enc_w     = (const float*)d_in[3];
  const float* enc_b     = (const float*)d_in[4];
  const float* dec_w     = (const float*)d_in[5];
  const float* dec_b     = (const float*)d_in[6];
  const float* pri_enc_w = (const float*)d_in[7];
  const float* pri_enc_b = (const float*)d_in[8];
  const float* gru_wi    = (const float*)d_in[9];
  const float* gru_bi    = (const float*)d_in[10];
  const float* gru_wh    = (const float*)d_in[11];
  const float* gru_bh    = (const float*)d_in[12];
  const float* pri_d1_w  = (const float*)d_in[13];
  const float* pri_d1_b  = (const float*)d_in[14];
  const float* pri_d2_w  = (const float*)d_in[15];
  const float* pri_d2_b  = (const float*)d_in[16];
  const float* pos_enc_w = (const float*)d_in[17];
  const float* pos_enc_b = (const float*)d_in[18];
  const float* pos_dec_w = (const float*)d_in[19];
  const float* pos_dec_b = (const float*)d_in[20];

  // ---- output sections (return order: stochs, dets, outs, q_sh, q_sc, p_sh, p_sc)
  float* out     = (float*)d_out;
  float* o_stoch = out;
  float* o_det   = o_stoch + (long)BT*64;
  float* o_outs  = o_det   + (long)BT*512;
  float* o_qsh   = o_outs  + (long)BT*66;
  float* o_qsc   = o_qsh   + (long)BT*64;
  float* o_psh   = o_qsc   + (long)BT*64;
  float* o_psc   = o_psh   + (long)BT*64;

  // ---- workspace carve-up (~147 MB fp32)
  float* w = (float*)d_ws;
  float* enc_wT     = w; w += 64*512;
  float* pri_enc_wT = w; w += 80*512;
  float* gru_wiT    = w; w += 512*1536;
  float* gru_whT    = w; w += 512*1536;
  float* pri_d1T    = w; w += 512*512;
  float* pri_d2T    = w; w += 512*128;
  float* pos_encT   = w; w += 1024*512;
  float* pos_decT   = w; w += 512*128;
  float* dec_wT     = w; w += 576*66;
  float* emb        = w; w += (long)BT*512;   // reused as px after the scan
  float* x_ws       = w; w += 128*512;
  float* gi_ws      = w; w += 128*1536;
  float* gh_ws      = w; w += 128*1536;
  float* qx1a       = w; w += 128*512;
  float* qx1b       = w; w += 128*512;
  float* qa         = w; w += 128*128;
  float* qb         = w; w += 128*128;

  // ---- pre-pass: transpose all weights to [K][N]
  {
    struct { const float* s; float* d; int R, C; } tps[9] = {
      {enc_w,     enc_wT,     512, 64  },
      {pri_enc_w, pri_enc_wT, 512, 80  },
      {gru_wi,    gru_wiT,    1536,512 },
      {gru_wh,    gru_whT,    1536,512 },
      {pri_d1_w,  pri_d1T,    512, 512 },
      {pri_d2_w,  pri_d2T,    128, 512 },
      {pos_enc_w, pos_encT,   512, 1024},
      {pos_dec_w, pos_decT,   128, 512 },
      {dec_w,     dec_wT,     66,  576 },
    };
    for (int i=0;i<9;i++){
      dim3 g((tps[i].C+31)/32, (tps[i].R+31)/32), b(32,8);
      hipLaunchKernelGGL(transpose_k, g, b, 0, stream, tps[i].s, tps[i].d, tps[i].R, tps[i].C);
    }
  }

  // ---- pre-pass: obs embedding  emb[b,t,:] = elu(obs @ enc_w^T + enc_b)
  {
    GemmP p{}; p.x1=obs; p.ldx1=64; p.split=64; p.w=enc_wT; p.ldw=512;
    p.bias=enc_b; p.out=emb; p.ldo=512; p.M=BT; p.N=512; p.K=64; p.k0=0;
    hipLaunchKernelGGL((gemm_k<SRC_CONCAT,EPI_ELU,64>), dim3(8,BT/64,1), dim3(256), 0, stream, p, p);
  }

  // ---- sequential scan over T
  for (int t=0; t<TDIM; ++t){
    // x = elu([stoch_{t-1}, act_t] @ pri_enc_w^T + b)   [128,512] K=80
    {
      GemmP p{};
      p.x1 = t ? (o_stoch + (long)(t-1)*64) : nullptr; p.ldx1 = (long)TDIM*64;
      p.x2 = act + (long)t*16;                         p.ldx2 = (long)TDIM*16;
      p.split = 64; p.w = pri_enc_wT; p.ldw = 512; p.bias = pri_enc_b;
      p.out = x_ws; p.ldo = 512; p.M = 128; p.N = 512; p.K = 80; p.k0 = 0;
      hipLaunchKernelGGL((gemm_k<SRC_CONCAT,EPI_ELU,16>), dim3(8,8,1), dim3(256), 0, stream, p, p);
    }
    // gi = x @ Wi^T + bi ;  gh = det_{t-1} @ Wh^T + bh   (z picks which)
    {
      GemmP p0{}; p0.x1 = x_ws; p0.ldx1 = 512; p0.split = 512;
      p0.w = gru_wiT; p0.ldw = 1536; p0.bias = gru_bi;
      p0.out = gi_ws; p0.ldo = 1536; p0.M = 128; p0.N = 1536; p0.K = 512; p0.k0 = 0;
      GemmP p1 = p0;
      p1.x1 = t ? (o_det + (long)(t-1)*512) : nullptr; p1.ldx1 = (long)TDIM*512;
      p1.w = gru_whT; p1.bias = gru_bh; p1.out = gh_ws;
      hipLaunchKernelGGL((gemm_k<SRC_CONCAT,EPI_PLAIN,16>), dim3(24,8,2), dim3(256), 0, stream, p0, p1);
    }
    // GRU gates -> det_t (written straight into the dets output section)
    hipLaunchKernelGGL(gate_k, dim3(256), dim3(256), 0, stream,
        gi_ws, gh_ws, t ? (o_det + (long)(t-1)*512) : nullptr, o_det + (long)t*512);
    // posterior hidden (K=1024 split in two partials over z)
    {
      GemmP p0{};
      p0.x1 = o_det + (long)t*512; p0.ldx1 = (long)TDIM*512;
      p0.x2 = emb   + (long)t*512; p0.ldx2 = (long)TDIM*512;
      p0.split = 512; p0.w = pos_encT; p0.ldw = 512;
      p0.out = qx1a; p0.ldo = 512; p0.M = 128; p0.N = 512; p0.K = 512; p0.k0 = 0;
      GemmP p1 = p0; p1.k0 = 512; p1.out = qx1b;
      hipLaunchKernelGGL((gemm_k<SRC_CONCAT,EPI_PARTIAL,16>), dim3(8,8,2), dim3(256), 0, stream, p0, p1);
    }
    // posterior head GEMM: X = elu(qx1a+qx1b+pos_enc_b), W = pos_dec (K split 2)
    {
      GemmP p0{};
      p0.x1 = qx1a; p0.ldx1 = 512; p0.x2 = qx1b; p0.ldx2 = 512; p0.biask = pos_enc_b;
      p0.w = pos_decT; p0.ldw = 128;
      p0.out = qa; p0.ldo = 128; p0.M = 128; p0.N = 128; p0.K = 256; p0.k0 = 0;
      GemmP p1 = p0; p1.k0 = 256; p1.out = qb;
      hipLaunchKernelGGL((gemm_k<SRC_ELUSUM,EPI_PARTIAL,16>), dim3(2,8,2), dim3(256), 0, stream, p0, p1);
    }
    // q_shift/q_scale/stoch
    hipLaunchKernelGGL(stoch_k, dim3(32), dim3(256), 0, stream,
        qa, qb, pos_dec_b, eps + (long)t*64,
        o_qsh + (long)t*64, o_qsc + (long)t*64, o_stoch + (long)t*64);
  }

  // ---- prior decode, hoisted out of the scan (parallel over all B*T)
  {
    GemmP p{}; p.x1 = o_det; p.ldx1 = 512; p.split = 512;
    p.w = pri_d1T; p.ldw = 512; p.bias = pri_d1_b;
    p.out = emb /* reuse as px */; p.ldo = 512; p.M = BT; p.N = 512; p.K = 512; p.k0 = 0;
    hipLaunchKernelGGL((gemm_k<SRC_CONCAT,EPI_ELU,64>), dim3(8,BT/64,1), dim3(256), 0, stream, p, p);
  }
  {
    GemmP p{}; p.x1 = emb; p.ldx1 = 512; p.split = 512;
    p.w = pri_d2T; p.ldw = 128; p.bias = pri_d2_b;
    p.out = o_psh; p.out2 = o_psc; p.M = BT; p.N = 128; p.K = 512; p.k0 = 0;
    hipLaunchKernelGGL((gemm_k<SRC_CONCAT,EPI_PSCALE,64>), dim3(2,BT/64,1), dim3(256), 0, stream, p, p);
  }
  // ---- final decoder: outs = [stoch, det] @ dec_w^T + dec_b   (N=66)
  {
    GemmP p{}; p.x1 = o_stoch; p.ldx1 = 64; p.x2 = o_det; p.ldx2 = 512; p.split = 64;
    p.w = dec_wT; p.ldw = 66; p.bias = dec_b;
    p.out = o_outs; p.ldo = 66; p.M = BT; p.N = 66; p.K = 576; p.k0 = 0;
    hipLaunchKernelGGL((gemm_k<SRC_CONCAT,EPI_PLAIN,64>), dim3(2,BT/64,1), dim3(256), 0, stream, p, p);
  }
}